// Round 2
// baseline (4794.450 us; speedup 1.0000x reference)
//
#include <hip/hip_runtime.h>
#include <stdint.h>
#include <stddef.h>

typedef __attribute__((ext_vector_type(8))) short short8;
typedef __attribute__((ext_vector_type(4))) short short4v;
typedef __attribute__((ext_vector_type(4))) float f32x4;

#define D_    768
#define HH    12
#define DHEAD 64
#define NP    576
#define BB    16
#define MROWS 9216      // BB*NP
#define KPAT  1216      // 1200 padded to multiple of 32
#define SCL   0.18033688011112042f   // 0.125 * log2(e)

static __device__ __forceinline__ unsigned short f2bf(float f){
  union { float f; unsigned int u; } v; v.f = f;
  unsigned int u = v.u;
  return (unsigned short)((u + 0x7FFFu + ((u >> 16) & 1u)) >> 16);
}

static __device__ __forceinline__ void gld16(const void* g, void* l){
  __builtin_amdgcn_global_load_lds((const __attribute__((address_space(1))) void*)g,
                                   (__attribute__((address_space(3))) void*)l,
                                   16, 0, 0);
}

// ---------------- GEMM: C[M,N] = A[M,K](bf16) @ W[N,K](bf16)^T + epilogue ----
__global__ __launch_bounds__(256) void gemm_bt(
    const unsigned short* __restrict__ A,
    const unsigned short* __restrict__ W,
    const float* __restrict__ bias,
    const float* __restrict__ pos,   // optional [576,768]
    const float* res,                // optional [M,N] (may alias outf!)
    float* outf,                     // optional
    unsigned short* outb,            // optional
    int M, int N, int K, int relu)
{
  __shared__ unsigned short sA[2][128*32];
  __shared__ unsigned short sB[2][128*32];
  const int NB = N >> 7;
  const int mb = blockIdx.x / NB;
  const int nb = blockIdx.x % NB;
  const int t = threadIdx.x;
  const int w = t >> 6, l = t & 63;
  const int m0 = mb << 7, n0 = nb << 7;

  const int srow = (w << 4) + (l >> 2);
  const int scol = (l & 3) << 3;
  const unsigned short* Ag = A + (size_t)(m0 + srow) * K + scol;
  const unsigned short* Wg = W + (size_t)(n0 + srow) * K + scol;
  const size_t g64 = (size_t)64 * K;

  const f32x4 zero = {0.f, 0.f, 0.f, 0.f};
  f32x4 acc[4][4];
  #pragma unroll
  for (int i = 0; i < 4; ++i)
    #pragma unroll
    for (int j = 0; j < 4; ++j) acc[i][j] = zero;

  const int KT = K >> 5;
  // prologue stage -> buf 0
  gld16(Ag,       &sA[0][((w<<4) +  0)*32]);
  gld16(Ag + g64, &sA[0][((w<<4) + 64)*32]);
  gld16(Wg,       &sB[0][((w<<4) +  0)*32]);
  gld16(Wg + g64, &sB[0][((w<<4) + 64)*32]);

  const int wr = w >> 1, wc = w & 1;
  const int fr = l & 15, fq = l >> 4;

  for (int kt = 0; kt < KT; ++kt){
    __syncthreads();                        // stage(cur) done + prev reads done
    if (kt + 1 < KT){
      const int nb2 = (kt + 1) & 1;
      const unsigned short* a0 = Ag + (size_t)(kt + 1) * 32;
      const unsigned short* w0 = Wg + (size_t)(kt + 1) * 32;
      gld16(a0,       &sA[nb2][((w<<4) +  0)*32]);
      gld16(a0 + g64, &sA[nb2][((w<<4) + 64)*32]);
      gld16(w0,       &sB[nb2][((w<<4) +  0)*32]);
      gld16(w0 + g64, &sB[nb2][((w<<4) + 64)*32]);
    }
    const int buf = kt & 1;
    short8 af[4], bv[4];
    #pragma unroll
    for (int mf = 0; mf < 4; ++mf)
      af[mf] = *(const short8*)&sA[buf][((wr<<6) + (mf<<4) + fr)*32 + (fq<<3)];
    #pragma unroll
    for (int nf = 0; nf < 4; ++nf)
      bv[nf] = *(const short8*)&sB[buf][((wc<<6) + (nf<<4) + fr)*32 + (fq<<3)];
    #pragma unroll
    for (int mf = 0; mf < 4; ++mf)
      #pragma unroll
      for (int nf = 0; nf < 4; ++nf)
        acc[mf][nf] = __builtin_amdgcn_mfma_f32_16x16x32_bf16(af[mf], bv[nf], acc[mf][nf], 0, 0, 0);
  }

  #pragma unroll
  for (int mf = 0; mf < 4; ++mf){
    #pragma unroll
    for (int nf = 0; nf < 4; ++nf){
      #pragma unroll
      for (int r = 0; r < 4; ++r){
        const int row = m0 + (wr<<6) + (mf<<4) + (fq<<2) + r;
        const int col = n0 + (wc<<6) + (nf<<4) + fr;
        float v = acc[mf][nf][r] + bias[col];
        if (pos)  v += pos[(size_t)(row % NP) * D_ + col];
        if (res)  v += res[(size_t)row * N + col];
        if (relu) v = fmaxf(v, 0.f);
        const size_t idx = (size_t)row * N + col;
        if (outf) outf[idx] = v;
        if (outb) outb[idx] = f2bf(v);
      }
    }
  }
}

// ---------------- fused attention, one (b,h) per block -----------------------
__global__ __launch_bounds__(384) void k_attn(const unsigned short* __restrict__ qkv,
                                              unsigned short* __restrict__ o)
{
  __shared__ unsigned short Kl[NP*DHEAD];      // [key][d], XOR-swizzled, 72KB
  __shared__ unsigned short Vt[DHEAD*NP];      // [d][key], XOR-swizzled, 72KB
  __shared__ unsigned short Pl[6][16*32];      // per-wave P tile
  const int bh = blockIdx.x;
  const int b = bh / HH, h = bh % HH;
  const unsigned short* base = qkv + (size_t)b * NP * 2304 + h * DHEAD;
  const int t = threadIdx.x;

  for (int cid = t; cid < 4608; cid += 384){   // stage K
    const int row = cid >> 3, g = cid & 7;
    short8 kv = *(const short8*)(base + 768 + (size_t)row * 2304 + (g << 3));
    const int off = (row << 7) + (((g << 4)) ^ ((row & 7) << 4));
    *(short8*)((char*)Kl + off) = kv;
  }
  for (int cid = t; cid < 4608; cid += 384){   // stage V transposed
    const int key = cid >> 3, g = cid & 7;
    short8 vv = *(const short8*)(base + 1536 + (size_t)key * 2304 + (g << 3));
    #pragma unroll
    for (int j = 0; j < 8; ++j){
      const int d = (g << 3) + j;
      const int off = (d * 1152 + (key << 1)) ^ ((d & 7) << 4);
      *(unsigned short*)((char*)Vt + off) = ((const unsigned short*)&vv)[j];
    }
  }
  __syncthreads();

  const int w = t >> 6, l = t & 63;
  const int fr = l & 15, fq = l >> 4;
  const f32x4 zero = {0.f, 0.f, 0.f, 0.f};

  for (int qi = 0; qi < 6; ++qi){
    const int q0 = (w + 6 * qi) << 4;
    const short8 qf0 = *(const short8*)(base + (size_t)(q0 + fr) * 2304 + (fq << 3));
    const short8 qf1 = *(const short8*)(base + (size_t)(q0 + fr) * 2304 + 32 + (fq << 3));
    float m = -1e30f, lsum = 0.f;
    f32x4 oa[4];
    #pragma unroll
    for (int nf = 0; nf < 4; ++nf) oa[nf] = zero;

    for (int kc = 0; kc < 18; ++kc){
      const int key0 = kc << 5;
      f32x4 s0 = zero, s1 = zero;
      {
        const int r0 = key0 + fr, r1 = key0 + 16 + fr;
        const int sw0 = (r0 & 7) << 4, sw1 = (r1 & 7) << 4;
        short8 k00 = *(const short8*)((char*)Kl + (r0 << 7) + (((fq << 4)     ) ^ sw0));
        short8 k01 = *(const short8*)((char*)Kl + (r0 << 7) + (((fq << 4) + 64) ^ sw0));
        short8 k10 = *(const short8*)((char*)Kl + (r1 << 7) + (((fq << 4)     ) ^ sw1));
        short8 k11 = *(const short8*)((char*)Kl + (r1 << 7) + (((fq << 4) + 64) ^ sw1));
        s0 = __builtin_amdgcn_mfma_f32_16x16x32_bf16(k00, qf0, s0, 0, 0, 0);
        s0 = __builtin_amdgcn_mfma_f32_16x16x32_bf16(k01, qf1, s0, 0, 0, 0);
        s1 = __builtin_amdgcn_mfma_f32_16x16x32_bf16(k10, qf0, s1, 0, 0, 0);
        s1 = __builtin_amdgcn_mfma_f32_16x16x32_bf16(k11, qf1, s1, 0, 0, 0);
      }
      // S^T[key][q]: lane holds keys {fq*4+r} and {16+fq*4+r} for q = fr
      float mx = fmaxf(fmaxf(fmaxf(s0[0], s0[1]), fmaxf(s0[2], s0[3])),
                       fmaxf(fmaxf(s1[0], s1[1]), fmaxf(s1[2], s1[3])));
      mx = fmaxf(mx, __shfl_xor(mx, 16));
      mx = fmaxf(mx, __shfl_xor(mx, 32));
      const float mb = mx * SCL;
      const float mn = fmaxf(m, mb);
      const float fc = exp2f(m - mn);
      const float p0 = exp2f(s0[0]*SCL - mn), p1 = exp2f(s0[1]*SCL - mn);
      const float p2 = exp2f(s0[2]*SCL - mn), p3 = exp2f(s0[3]*SCL - mn);
      const float p4 = exp2f(s1[0]*SCL - mn), p5 = exp2f(s1[1]*SCL - mn);
      const float p6 = exp2f(s1[2]*SCL - mn), p7 = exp2f(s1[3]*SCL - mn);
      float ps = ((p0+p1)+(p2+p3)) + ((p4+p5)+(p6+p7));
      ps += __shfl_xor(ps, 16);
      ps += __shfl_xor(ps, 32);
      lsum = lsum * fc + ps;
      m = mn;
      if (!__all(fc == 1.0f)){
        const float fA = __shfl(fc, (fq<<2) + 0);
        const float fB = __shfl(fc, (fq<<2) + 1);
        const float fC = __shfl(fc, (fq<<2) + 2);
        const float fD = __shfl(fc, (fq<<2) + 3);
        #pragma unroll
        for (int nf = 0; nf < 4; ++nf){
          oa[nf][0] *= fA; oa[nf][1] *= fB; oa[nf][2] *= fC; oa[nf][3] *= fD;
        }
      }
      const short4v pv0 = { (short)f2bf(p0), (short)f2bf(p1), (short)f2bf(p2), (short)f2bf(p3) };
      const short4v pv1 = { (short)f2bf(p4), (short)f2bf(p5), (short)f2bf(p6), (short)f2bf(p7) };
      *(short4v*)&Pl[w][(fr<<5) + (fq<<2)]      = pv0;
      *(short4v*)&Pl[w][(fr<<5) + 16 + (fq<<2)] = pv1;
      asm volatile("" ::: "memory");
      const short8 pa = *(const short8*)&Pl[w][(fr<<5) + (fq<<3)];
      #pragma unroll
      for (int nf = 0; nf < 4; ++nf){
        const int d = (nf << 4) + fr;
        const int off = (d * 1152 + ((key0 + (fq << 3)) << 1)) ^ ((d & 7) << 4);
        const short8 vf = *(const short8*)((char*)Vt + off);
        oa[nf] = __builtin_amdgcn_mfma_f32_16x16x32_bf16(pa, vf, oa[nf], 0, 0, 0);
      }
    }
    const float rl = 1.f / lsum;
    const float rA = __shfl(rl, (fq<<2)+0), rB = __shfl(rl, (fq<<2)+1);
    const float rC = __shfl(rl, (fq<<2)+2), rD = __shfl(rl, (fq<<2)+3);
    #pragma unroll
    for (int nf = 0; nf < 4; ++nf){
      const int col = h * DHEAD + (nf << 4) + fr;
      const size_t r0 = (size_t)(b * NP + q0 + (fq << 2));
      o[(r0 + 0) * D_ + col] = f2bf(oa[nf][0] * rA);
      o[(r0 + 1) * D_ + col] = f2bf(oa[nf][1] * rB);
      o[(r0 + 2) * D_ + col] = f2bf(oa[nf][2] * rC);
      o[(r0 + 3) * D_ + col] = f2bf(oa[nf][3] * rD);
    }
  }
}

// ---------------- small kernels ----------------------------------------------
__global__ void k_f2b(const float* __restrict__ s, unsigned short* __restrict__ d, long n){
  long i = (long)blockIdx.x * blockDim.x + threadIdx.x;
  const long st = (long)gridDim.x * blockDim.x;
  for (; i < n; i += st) d[i] = f2bf(s[i]);
}

__global__ void k_pack_qkvw(const float* __restrict__ Wq, const float* __restrict__ Wk,
                            const float* __restrict__ Wv, unsigned short* __restrict__ dst){
  const long n = (long)12 * 2304 * 768;
  long i = (long)blockIdx.x * blockDim.x + threadIdx.x;
  const long st = (long)gridDim.x * blockDim.x;
  for (; i < n; i += st){
    const int lay = (int)(i / (2304 * 768));
    const int rem = (int)(i % (2304 * 768));
    const int r = rem / 768, k = rem % 768;
    // NOTE: 768 is NOT pow2 — must use real modulo, not &767 (round-1 bug)
    const float* s = (r < 768) ? Wq : ((r < 1536) ? Wk : Wv);
    const int rr = (r < 768) ? r : ((r < 1536) ? r - 768 : r - 1536);
    dst[i] = f2bf(s[(size_t)lay * 589824 + (size_t)rr * 768 + k]);
  }
}

__global__ void k_pack_qkvb(const float* __restrict__ bq, const float* __restrict__ bk,
                            const float* __restrict__ bv, float* __restrict__ dst){
  const int i = blockIdx.x * 256 + threadIdx.x;
  if (i >= 12 * 2304) return;
  const int lay = i / 2304, r = i % 2304;
  const float* s = (r < 768) ? bq : ((r < 1536) ? bk : bv);
  const int rr = (r < 768) ? r : ((r < 1536) ? r - 768 : r - 1536);
  dst[i] = s[lay * 768 + rr];
}

__global__ void k_patchw(const float* __restrict__ s, unsigned short* __restrict__ d){
  const long n = (long)768 * KPAT;
  long i = (long)blockIdx.x * blockDim.x + threadIdx.x;
  const long st = (long)gridDim.x * blockDim.x;
  for (; i < n; i += st){
    const int r = (int)(i / KPAT), k = (int)(i % KPAT);
    d[i] = (k < 1200) ? f2bf(s[(size_t)r * 1200 + k]) : (unsigned short)0;
  }
}

__global__ void k_patches(const float* __restrict__ x, unsigned short* __restrict__ d){
  const long n = (long)MROWS * KPAT;
  long i = (long)blockIdx.x * blockDim.x + threadIdx.x;
  const long st = (long)gridDim.x * blockDim.x;
  for (; i < n; i += st){
    const int mrow = (int)(i / KPAT), k = (int)(i % KPAT);
    unsigned short v = 0;
    if (k < 1200){
      const int c = k / 400, rem = k % 400, py = rem / 20, px = rem % 20;
      const int b = mrow / NP, pn = mrow % NP, hp = pn / 18, wp = pn % 18;
      v = f2bf(x[(((size_t)b * 3 + c) * 640 + hp * 20 + py) * 360 + wp * 20 + px]);
    }
    d[i] = v;
  }
}

__global__ __launch_bounds__(256) void k_ln(float* h, unsigned short* hb,
                                            const float* __restrict__ g,
                                            const float* __restrict__ bt){
  const int r = blockIdx.x, t = threadIdx.x;
  const size_t base = (size_t)r * D_;
  const float x0 = h[base + t], x1 = h[base + t + 256], x2 = h[base + t + 512];
  float s = x0 + x1 + x2;
  #pragma unroll
  for (int o = 1; o < 64; o <<= 1) s += __shfl_xor(s, o);
  __shared__ float red[8];
  const int w = t >> 6, l = t & 63;
  if (l == 0) red[w] = s;
  __syncthreads();
  const float mu = (red[0] + red[1] + red[2] + red[3]) * (1.f / 768.f);
  const float d0 = x0 - mu, d1 = x1 - mu, d2 = x2 - mu;
  float v = d0*d0 + d1*d1 + d2*d2;
  #pragma unroll
  for (int o = 1; o < 64; o <<= 1) v += __shfl_xor(v, o);
  if (l == 0) red[4 + w] = v;
  __syncthreads();
  const float var = (red[4] + red[5] + red[6] + red[7]) * (1.f / 768.f);
  const float rs = rsqrtf(var + 1e-5f);
  const float y0 = d0 * rs * g[t]       + bt[t];
  const float y1 = d1 * rs * g[t + 256] + bt[t + 256];
  const float y2 = d2 * rs * g[t + 512] + bt[t + 512];
  h[base + t] = y0; h[base + t + 256] = y1; h[base + t + 512] = y2;
  hb[base + t] = f2bf(y0); hb[base + t + 256] = f2bf(y1); hb[base + t + 512] = f2bf(y2);
}

__global__ void k_pool(const float* __restrict__ h, float* __restrict__ p){
  const int i = blockIdx.x * 256 + threadIdx.x;   // 12288
  const int b = i / D_, c = i % D_;
  const float* base = h + (size_t)b * NP * D_ + c;
  float s = 0.f;
  for (int n = 0; n < NP; ++n) s += base[(size_t)n * D_];
  p[i] = s * (1.f / 576.f);
}

__global__ __launch_bounds__(64) void k_fc(const float* __restrict__ p, const float* __restrict__ w,
                                           const float* __restrict__ bias, float* __restrict__ out){
  const int oi = blockIdx.x;                       // 160
  const int b = oi / 10, j = oi % 10;
  const int l = threadIdx.x;
  float s = 0.f;
  for (int c = l; c < D_; c += 64) s += p[b * D_ + c] * w[j * D_ + c];
  #pragma unroll
  for (int o = 1; o < 64; o <<= 1) s += __shfl_xor(s, o);
  if (l == 0) out[oi] = s + bias[j];
}

// ---------------- launch ------------------------------------------------------
extern "C" void kernel_launch(void* const* d_in, const int* in_sizes, int n_in,
                              void* d_out, int out_size, void* d_ws, size_t ws_size,
                              hipStream_t stream)
{
  const float* x       = (const float*)d_in[0];
  const float* patch_w = (const float*)d_in[1];
  const float* patch_b = (const float*)d_in[2];
  const float* pos_emb = (const float*)d_in[3];
  const float* ln_g    = (const float*)d_in[4];
  const float* ln_b    = (const float*)d_in[5];
  const float* Wq      = (const float*)d_in[6];
  const float* bq      = (const float*)d_in[7];
  const float* Wk      = (const float*)d_in[8];
  const float* bk      = (const float*)d_in[9];
  const float* Wv      = (const float*)d_in[10];
  const float* bv      = (const float*)d_in[11];
  const float* Wo      = (const float*)d_in[12];
  const float* bo      = (const float*)d_in[13];
  const float* W1      = (const float*)d_in[14];
  const float* b1      = (const float*)d_in[15];
  const float* W2      = (const float*)d_in[16];
  const float* b2      = (const float*)d_in[17];
  const float* fc_w    = (const float*)d_in[18];
  const float* fc_b    = (const float*)d_in[19];
  float* out = (float*)d_out;
  (void)in_sizes; (void)n_in; (void)out_size; (void)ws_size;

  char* ws = (char*)d_ws;
  size_t off = 0;
  auto alloc = [&](size_t bytes) -> char* {
    char* p = ws + off;
    off += (bytes + 255) & ~(size_t)255;
    return p;
  };
  unsigned short* wqkv    = (unsigned short*)alloc((size_t)12*2304*768*2);
  unsigned short* wo      = (unsigned short*)alloc((size_t)12*768*768*2);
  unsigned short* w1      = (unsigned short*)alloc((size_t)12*3072*768*2);
  unsigned short* w2      = (unsigned short*)alloc((size_t)12*768*3072*2);
  unsigned short* wp      = (unsigned short*)alloc((size_t)768*KPAT*2);
  float*          bqkv    = (float*)alloc((size_t)12*2304*4);
  unsigned short* patches = (unsigned short*)alloc((size_t)MROWS*KPAT*2);
  float*          hf      = (float*)alloc((size_t)MROWS*D_*4);
  unsigned short* hb      = (unsigned short*)alloc((size_t)MROWS*D_*2);
  unsigned short* qkvb    = (unsigned short*)alloc((size_t)MROWS*2304*2);
  unsigned short* ob      = (unsigned short*)alloc((size_t)MROWS*D_*2);
  unsigned short* ffb     = (unsigned short*)alloc((size_t)MROWS*3072*2);
  float*          pooled  = (float*)alloc((size_t)16*D_*4);

  // weight conversion / packing (bf16)
  k_pack_qkvw<<<2048, 256, 0, stream>>>(Wq, Wk, Wv, wqkv);
  k_pack_qkvb<<<(12*2304 + 255)/256, 256, 0, stream>>>(bq, bk, bv, bqkv);
  k_f2b<<<2048, 256, 0, stream>>>(Wo, wo, (long)12*768*768);
  k_f2b<<<2048, 256, 0, stream>>>(W1, w1, (long)12*3072*768);
  k_f2b<<<2048, 256, 0, stream>>>(W2, w2, (long)12*768*3072);
  k_patchw<<<2048, 256, 0, stream>>>(patch_w, wp);
  k_patches<<<2048, 256, 0, stream>>>(x, patches);

  // patch embed (+bias +pos) -> hf ; LN -> hf (in-place) + hb
  gemm_bt<<<72*6, 256, 0, stream>>>(patches, wp, patch_b, pos_emb,
                                    nullptr, hf, nullptr, MROWS, 768, KPAT, 0);
  k_ln<<<MROWS, 256, 0, stream>>>(hf, hb, ln_g, ln_b);

  for (int l = 0; l < 12; ++l){
    gemm_bt<<<72*18, 256, 0, stream>>>(hb, wqkv + (size_t)l*2304*768, bqkv + l*2304,
                                       nullptr, nullptr, nullptr, qkvb, MROWS, 2304, 768, 0);
    k_attn<<<192, 384, 0, stream>>>(qkvb, ob);
    gemm_bt<<<72*6, 256, 0, stream>>>(ob, wo + (size_t)l*768*768, bo + l*768,
                                      nullptr, hf, hf, hb, MROWS, 768, 768, 0);
    gemm_bt<<<72*24, 256, 0, stream>>>(hb, w1 + (size_t)l*3072*768, b1 + (size_t)l*3072,
                                       nullptr, nullptr, nullptr, ffb, MROWS, 3072, 768, 1);
    gemm_bt<<<72*6, 256, 0, stream>>>(ffb, w2 + (size_t)l*768*3072, b2 + l*768,
                                      nullptr, hf, hf, hb, MROWS, 768, 3072, 0);
  }
  k_pool<<<48, 256, 0, stream>>>(hf, pooled);
  k_fc<<<160, 64, 0, stream>>>(pooled, fc_w, fc_b, out);
}

// Round 3
// 4706.215 us; speedup vs baseline: 1.0187x; 1.0187x over previous
//
#include <hip/hip_runtime.h>
#include <stdint.h>
#include <stddef.h>

typedef __attribute__((ext_vector_type(8))) short short8;
typedef __attribute__((ext_vector_type(4))) short short4v;
typedef __attribute__((ext_vector_type(4))) float f32x4;

#define D_    768
#define HH    12
#define DHEAD 64
#define NP    576
#define BB    16
#define MROWS 9216      // BB*NP
#define KPAT  1216      // 1200 padded to multiple of 32
#define SCL   0.18033688011112042f   // 0.125 * log2(e)

static __device__ __forceinline__ unsigned short f2bf(float f){
  union { float f; unsigned int u; } v; v.f = f;
  unsigned int u = v.u;
  return (unsigned short)((u + 0x7FFFu + ((u >> 16) & 1u)) >> 16);
}

static __device__ __forceinline__ void gld16(const void* g, void* l){
  __builtin_amdgcn_global_load_lds((const __attribute__((address_space(1))) void*)g,
                                   (__attribute__((address_space(3))) void*)l,
                                   16, 0, 0);
}

// ---------------- GEMM: C[M,N] = A[M,K](bf16) @ W[N,K](bf16)^T + epilogue ----
// T1: bijective XCD chunking (requires gridDim.x % 8 == 0 — true for all uses).
// T2: LDS 16B-block XOR swizzle, pre-swizzled on the global source side.
__global__ __launch_bounds__(256) void gemm_bt(
    const unsigned short* __restrict__ A,
    const unsigned short* __restrict__ W,
    const float* __restrict__ bias,
    const float* __restrict__ pos,   // optional [576,768]
    const float* res,                // optional [M,N] (may alias outf!)
    float* outf,                     // optional
    unsigned short* outb,            // optional
    int M, int N, int K, int relu)
{
  __shared__ unsigned short sA[2][128*32];
  __shared__ unsigned short sB[2][128*32];
  const int NB = N >> 7;
  const int nwg = (int)gridDim.x;
  int wid = (int)blockIdx.x;
  wid = (wid & 7) * (nwg >> 3) + (wid >> 3);   // XCD chunk: contiguous wids per XCD
  const int mb = wid / NB;
  const int nb = wid % NB;
  const int t = threadIdx.x;
  const int w = t >> 6, l = t & 63;
  const int m0 = mb << 7, n0 = nb << 7;

  const int srow = (w << 4) + (l >> 2);
  const int scb  = (l & 3) ^ ((l >> 2) & 3);   // pre-swizzled 16B-block index
  const unsigned short* Ag = A + (size_t)(m0 + srow) * K + (scb << 3);
  const unsigned short* Wg = W + (size_t)(n0 + srow) * K + (scb << 3);
  const size_t g64 = (size_t)64 * K;

  const f32x4 zero = {0.f, 0.f, 0.f, 0.f};
  f32x4 acc[4][4];
  #pragma unroll
  for (int i = 0; i < 4; ++i)
    #pragma unroll
    for (int j = 0; j < 4; ++j) acc[i][j] = zero;

  const int KT = K >> 5;
  // prologue stage -> buf 0
  gld16(Ag,       &sA[0][((w<<4) +  0)*32]);
  gld16(Ag + g64, &sA[0][((w<<4) + 64)*32]);
  gld16(Wg,       &sB[0][((w<<4) +  0)*32]);
  gld16(Wg + g64, &sB[0][((w<<4) + 64)*32]);

  const int wr = w >> 1, wc = w & 1;
  const int fr = l & 15, fq = l >> 4;
  const int fsw = (fq ^ (fr & 3)) << 3;        // read-side swizzled k-block offset

  for (int kt = 0; kt < KT; ++kt){
    __syncthreads();                        // stage(cur) done + prev reads done
    if (kt + 1 < KT){
      const int nb2 = (kt + 1) & 1;
      const unsigned short* a0 = Ag + (size_t)(kt + 1) * 32;
      const unsigned short* w0 = Wg + (size_t)(kt + 1) * 32;
      gld16(a0,       &sA[nb2][((w<<4) +  0)*32]);
      gld16(a0 + g64, &sA[nb2][((w<<4) + 64)*32]);
      gld16(w0,       &sB[nb2][((w<<4) +  0)*32]);
      gld16(w0 + g64, &sB[nb2][((w<<4) + 64)*32]);
    }
    const int buf = kt & 1;
    short8 af[4], bv[4];
    #pragma unroll
    for (int mf = 0; mf < 4; ++mf)
      af[mf] = *(const short8*)&sA[buf][((wr<<6) + (mf<<4) + fr)*32 + fsw];
    #pragma unroll
    for (int nf = 0; nf < 4; ++nf)
      bv[nf] = *(const short8*)&sB[buf][((wc<<6) + (nf<<4) + fr)*32 + fsw];
    #pragma unroll
    for (int mf = 0; mf < 4; ++mf)
      #pragma unroll
      for (int nf = 0; nf < 4; ++nf)
        acc[mf][nf] = __builtin_amdgcn_mfma_f32_16x16x32_bf16(af[mf], bv[nf], acc[mf][nf], 0, 0, 0);
  }

  #pragma unroll
  for (int mf = 0; mf < 4; ++mf){
    #pragma unroll
    for (int nf = 0; nf < 4; ++nf){
      #pragma unroll
      for (int r = 0; r < 4; ++r){
        const int row = m0 + (wr<<6) + (mf<<4) + (fq<<2) + r;
        const int col = n0 + (wc<<6) + (nf<<4) + fr;
        float v = acc[mf][nf][r] + bias[col];
        if (pos)  v += pos[(size_t)(row % NP) * D_ + col];
        if (res)  v += res[(size_t)row * N + col];
        if (relu) v = fmaxf(v, 0.f);
        const size_t idx = (size_t)row * N + col;
        if (outf) outf[idx] = v;
        if (outb) outb[idx] = f2bf(v);
      }
    }
  }
}

// ---------------- fused attention, one (b,h) per block -----------------------
__global__ __launch_bounds__(384) void k_attn(const unsigned short* __restrict__ qkv,
                                              unsigned short* __restrict__ o)
{
  __shared__ unsigned short Kl[NP*DHEAD];      // [key][d], XOR-swizzled, 72KB
  __shared__ unsigned short Vt[DHEAD*NP];      // [d][key], XOR-swizzled, 72KB
  __shared__ unsigned short Pl[6][16*32];      // per-wave P tile
  const int bh = blockIdx.x;
  const int b = bh / HH, h = bh % HH;
  const unsigned short* base = qkv + (size_t)b * NP * 2304 + h * DHEAD;
  const int t = threadIdx.x;

  for (int cid = t; cid < 4608; cid += 384){   // stage K
    const int row = cid >> 3, g = cid & 7;
    short8 kv = *(const short8*)(base + 768 + (size_t)row * 2304 + (g << 3));
    const int off = (row << 7) + (((g << 4)) ^ ((row & 7) << 4));
    *(short8*)((char*)Kl + off) = kv;
  }
  for (int cid = t; cid < 4608; cid += 384){   // stage V transposed
    const int key = cid >> 3, g = cid & 7;
    short8 vv = *(const short8*)(base + 1536 + (size_t)key * 2304 + (g << 3));
    #pragma unroll
    for (int j = 0; j < 8; ++j){
      const int d = (g << 3) + j;
      const int off = (d * 1152 + (key << 1)) ^ ((d & 7) << 4);
      *(unsigned short*)((char*)Vt + off) = ((const unsigned short*)&vv)[j];
    }
  }
  __syncthreads();

  const int w = t >> 6, l = t & 63;
  const int fr = l & 15, fq = l >> 4;
  const f32x4 zero = {0.f, 0.f, 0.f, 0.f};

  for (int qi = 0; qi < 6; ++qi){
    const int q0 = (w + 6 * qi) << 4;
    const short8 qf0 = *(const short8*)(base + (size_t)(q0 + fr) * 2304 + (fq << 3));
    const short8 qf1 = *(const short8*)(base + (size_t)(q0 + fr) * 2304 + 32 + (fq << 3));
    float m = -1e30f, lsum = 0.f;
    f32x4 oa[4];
    #pragma unroll
    for (int nf = 0; nf < 4; ++nf) oa[nf] = zero;

    for (int kc = 0; kc < 18; ++kc){
      const int key0 = kc << 5;
      f32x4 s0 = zero, s1 = zero;
      {
        const int r0 = key0 + fr, r1 = key0 + 16 + fr;
        const int sw0 = (r0 & 7) << 4, sw1 = (r1 & 7) << 4;
        short8 k00 = *(const short8*)((char*)Kl + (r0 << 7) + (((fq << 4)     ) ^ sw0));
        short8 k01 = *(const short8*)((char*)Kl + (r0 << 7) + (((fq << 4) + 64) ^ sw0));
        short8 k10 = *(const short8*)((char*)Kl + (r1 << 7) + (((fq << 4)     ) ^ sw1));
        short8 k11 = *(const short8*)((char*)Kl + (r1 << 7) + (((fq << 4) + 64) ^ sw1));
        s0 = __builtin_amdgcn_mfma_f32_16x16x32_bf16(k00, qf0, s0, 0, 0, 0);
        s0 = __builtin_amdgcn_mfma_f32_16x16x32_bf16(k01, qf1, s0, 0, 0, 0);
        s1 = __builtin_amdgcn_mfma_f32_16x16x32_bf16(k10, qf0, s1, 0, 0, 0);
        s1 = __builtin_amdgcn_mfma_f32_16x16x32_bf16(k11, qf1, s1, 0, 0, 0);
      }
      // S^T[key][q]: lane holds keys {fq*4+r} and {16+fq*4+r} for q = fr
      float mx = fmaxf(fmaxf(fmaxf(s0[0], s0[1]), fmaxf(s0[2], s0[3])),
                       fmaxf(fmaxf(s1[0], s1[1]), fmaxf(s1[2], s1[3])));
      mx = fmaxf(mx, __shfl_xor(mx, 16));
      mx = fmaxf(mx, __shfl_xor(mx, 32));
      const float mb = mx * SCL;
      const float mn = fmaxf(m, mb);
      const float fc = exp2f(m - mn);
      const float p0 = exp2f(s0[0]*SCL - mn), p1 = exp2f(s0[1]*SCL - mn);
      const float p2 = exp2f(s0[2]*SCL - mn), p3 = exp2f(s0[3]*SCL - mn);
      const float p4 = exp2f(s1[0]*SCL - mn), p5 = exp2f(s1[1]*SCL - mn);
      const float p6 = exp2f(s1[2]*SCL - mn), p7 = exp2f(s1[3]*SCL - mn);
      float ps = ((p0+p1)+(p2+p3)) + ((p4+p5)+(p6+p7));
      ps += __shfl_xor(ps, 16);
      ps += __shfl_xor(ps, 32);
      lsum = lsum * fc + ps;
      m = mn;
      if (!__all(fc == 1.0f)){
        const float fA = __shfl(fc, (fq<<2) + 0);
        const float fB = __shfl(fc, (fq<<2) + 1);
        const float fC = __shfl(fc, (fq<<2) + 2);
        const float fD = __shfl(fc, (fq<<2) + 3);
        #pragma unroll
        for (int nf = 0; nf < 4; ++nf){
          oa[nf][0] *= fA; oa[nf][1] *= fB; oa[nf][2] *= fC; oa[nf][3] *= fD;
        }
      }
      const short4v pv0 = { (short)f2bf(p0), (short)f2bf(p1), (short)f2bf(p2), (short)f2bf(p3) };
      const short4v pv1 = { (short)f2bf(p4), (short)f2bf(p5), (short)f2bf(p6), (short)f2bf(p7) };
      *(short4v*)&Pl[w][(fr<<5) + (fq<<2)]      = pv0;
      *(short4v*)&Pl[w][(fr<<5) + 16 + (fq<<2)] = pv1;
      asm volatile("" ::: "memory");
      const short8 pa = *(const short8*)&Pl[w][(fr<<5) + (fq<<3)];
      #pragma unroll
      for (int nf = 0; nf < 4; ++nf){
        const int d = (nf << 4) + fr;
        const int off = (d * 1152 + ((key0 + (fq << 3)) << 1)) ^ ((d & 7) << 4);
        const short8 vf = *(const short8*)((char*)Vt + off);
        oa[nf] = __builtin_amdgcn_mfma_f32_16x16x32_bf16(pa, vf, oa[nf], 0, 0, 0);
      }
    }
    const float rl = 1.f / lsum;
    const float rA = __shfl(rl, (fq<<2)+0), rB = __shfl(rl, (fq<<2)+1);
    const float rC = __shfl(rl, (fq<<2)+2), rD = __shfl(rl, (fq<<2)+3);
    #pragma unroll
    for (int nf = 0; nf < 4; ++nf){
      const int col = h * DHEAD + (nf << 4) + fr;
      const size_t r0 = (size_t)(b * NP + q0 + (fq << 2));
      o[(r0 + 0) * D_ + col] = f2bf(oa[nf][0] * rA);
      o[(r0 + 1) * D_ + col] = f2bf(oa[nf][1] * rB);
      o[(r0 + 2) * D_ + col] = f2bf(oa[nf][2] * rC);
      o[(r0 + 3) * D_ + col] = f2bf(oa[nf][3] * rD);
    }
  }
}

// ---------------- small kernels ----------------------------------------------
__global__ void k_f2b(const float* __restrict__ s, unsigned short* __restrict__ d, long n){
  long i = (long)blockIdx.x * blockDim.x + threadIdx.x;
  const long st = (long)gridDim.x * blockDim.x;
  for (; i < n; i += st) d[i] = f2bf(s[i]);
}

__global__ void k_pack_qkvw(const float* __restrict__ Wq, const float* __restrict__ Wk,
                            const float* __restrict__ Wv, unsigned short* __restrict__ dst){
  const long n = (long)12 * 2304 * 768;
  long i = (long)blockIdx.x * blockDim.x + threadIdx.x;
  const long st = (long)gridDim.x * blockDim.x;
  for (; i < n; i += st){
    const int lay = (int)(i / (2304 * 768));
    const int rem = (int)(i % (2304 * 768));
    const int r = rem / 768, k = rem % 768;
    // NOTE: 768 is NOT pow2 — must use real modulo, not &767 (round-1 bug)
    const float* s = (r < 768) ? Wq : ((r < 1536) ? Wk : Wv);
    const int rr = (r < 768) ? r : ((r < 1536) ? r - 768 : r - 1536);
    dst[i] = f2bf(s[(size_t)lay * 589824 + (size_t)rr * 768 + k]);
  }
}

__global__ void k_pack_qkvb(const float* __restrict__ bq, const float* __restrict__ bk,
                            const float* __restrict__ bv, float* __restrict__ dst){
  const int i = blockIdx.x * 256 + threadIdx.x;
  if (i >= 12 * 2304) return;
  const int lay = i / 2304, r = i % 2304;
  const float* s = (r < 768) ? bq : ((r < 1536) ? bk : bv);
  const int rr = (r < 768) ? r : ((r < 1536) ? r - 768 : r - 1536);
  dst[i] = s[lay * 768 + rr];
}

__global__ void k_patchw(const float* __restrict__ s, unsigned short* __restrict__ d){
  const long n = (long)768 * KPAT;
  long i = (long)blockIdx.x * blockDim.x + threadIdx.x;
  const long st = (long)gridDim.x * blockDim.x;
  for (; i < n; i += st){
    const int r = (int)(i / KPAT), k = (int)(i % KPAT);
    d[i] = (k < 1200) ? f2bf(s[(size_t)r * 1200 + k]) : (unsigned short)0;
  }
}

__global__ void k_patches(const float* __restrict__ x, unsigned short* __restrict__ d){
  const long n = (long)MROWS * KPAT;
  long i = (long)blockIdx.x * blockDim.x + threadIdx.x;
  const long st = (long)gridDim.x * blockDim.x;
  for (; i < n; i += st){
    const int mrow = (int)(i / KPAT), k = (int)(i % KPAT);
    unsigned short v = 0;
    if (k < 1200){
      const int c = k / 400, rem = k % 400, py = rem / 20, px = rem % 20;
      const int b = mrow / NP, pn = mrow % NP, hp = pn / 18, wp = pn % 18;
      v = f2bf(x[(((size_t)b * 3 + c) * 640 + hp * 20 + py) * 360 + wp * 20 + px]);
    }
    d[i] = v;
  }
}

__global__ __launch_bounds__(256) void k_ln(float* h, unsigned short* hb,
                                            const float* __restrict__ g,
                                            const float* __restrict__ bt){
  const int r = blockIdx.x, t = threadIdx.x;
  const size_t base = (size_t)r * D_;
  const float x0 = h[base + t], x1 = h[base + t + 256], x2 = h[base + t + 512];
  float s = x0 + x1 + x2;
  #pragma unroll
  for (int o = 1; o < 64; o <<= 1) s += __shfl_xor(s, o);
  __shared__ float red[8];
  const int w = t >> 6, l = t & 63;
  if (l == 0) red[w] = s;
  __syncthreads();
  const float mu = (red[0] + red[1] + red[2] + red[3]) * (1.f / 768.f);
  const float d0 = x0 - mu, d1 = x1 - mu, d2 = x2 - mu;
  float v = d0*d0 + d1*d1 + d2*d2;
  #pragma unroll
  for (int o = 1; o < 64; o <<= 1) v += __shfl_xor(v, o);
  if (l == 0) red[4 + w] = v;
  __syncthreads();
  const float var = (red[4] + red[5] + red[6] + red[7]) * (1.f / 768.f);
  const float rs = rsqrtf(var + 1e-5f);
  const float y0 = d0 * rs * g[t]       + bt[t];
  const float y1 = d1 * rs * g[t + 256] + bt[t + 256];
  const float y2 = d2 * rs * g[t + 512] + bt[t + 512];
  h[base + t] = y0; h[base + t + 256] = y1; h[base + t + 512] = y2;
  hb[base + t] = f2bf(y0); hb[base + t + 256] = f2bf(y1); hb[base + t + 512] = f2bf(y2);
}

__global__ void k_pool(const float* __restrict__ h, float* __restrict__ p){
  const int i = blockIdx.x * 256 + threadIdx.x;   // 12288
  const int b = i / D_, c = i % D_;
  const float* base = h + (size_t)b * NP * D_ + c;
  float s = 0.f;
  for (int n = 0; n < NP; ++n) s += base[(size_t)n * D_];
  p[i] = s * (1.f / 576.f);
}

__global__ __launch_bounds__(64) void k_fc(const float* __restrict__ p, const float* __restrict__ w,
                                           const float* __restrict__ bias, float* __restrict__ out){
  const int oi = blockIdx.x;                       // 160
  const int b = oi / 10, j = oi % 10;
  const int l = threadIdx.x;
  float s = 0.f;
  for (int c = l; c < D_; c += 64) s += p[b * D_ + c] * w[j * D_ + c];
  #pragma unroll
  for (int o = 1; o < 64; o <<= 1) s += __shfl_xor(s, o);
  if (l == 0) out[oi] = s + bias[j];
}

// ---------------- launch ------------------------------------------------------
extern "C" void kernel_launch(void* const* d_in, const int* in_sizes, int n_in,
                              void* d_out, int out_size, void* d_ws, size_t ws_size,
                              hipStream_t stream)
{
  const float* x       = (const float*)d_in[0];
  const float* patch_w = (const float*)d_in[1];
  const float* patch_b = (const float*)d_in[2];
  const float* pos_emb = (const float*)d_in[3];
  const float* ln_g    = (const float*)d_in[4];
  const float* ln_b    = (const float*)d_in[5];
  const float* Wq      = (const float*)d_in[6];
  const float* bq      = (const float*)d_in[7];
  const float* Wk      = (const float*)d_in[8];
  const float* bk      = (const float*)d_in[9];
  const float* Wv      = (const float*)d_in[10];
  const float* bv      = (const float*)d_in[11];
  const float* Wo      = (const float*)d_in[12];
  const float* bo      = (const float*)d_in[13];
  const float* W1      = (const float*)d_in[14];
  const float* b1      = (const float*)d_in[15];
  const float* W2      = (const float*)d_in[16];
  const float* b2      = (const float*)d_in[17];
  const float* fc_w    = (const float*)d_in[18];
  const float* fc_b    = (const float*)d_in[19];
  float* out = (float*)d_out;
  (void)in_sizes; (void)n_in; (void)out_size; (void)ws_size;

  char* ws = (char*)d_ws;
  size_t off = 0;
  auto alloc = [&](size_t bytes) -> char* {
    char* p = ws + off;
    off += (bytes + 255) & ~(size_t)255;
    return p;
  };
  unsigned short* wqkv    = (unsigned short*)alloc((size_t)12*2304*768*2);
  unsigned short* wo      = (unsigned short*)alloc((size_t)12*768*768*2);
  unsigned short* w1      = (unsigned short*)alloc((size_t)12*3072*768*2);
  unsigned short* w2      = (unsigned short*)alloc((size_t)12*768*3072*2);
  unsigned short* wp      = (unsigned short*)alloc((size_t)768*KPAT*2);
  float*          bqkv    = (float*)alloc((size_t)12*2304*4);
  unsigned short* patches = (unsigned short*)alloc((size_t)MROWS*KPAT*2);
  float*          hf      = (float*)alloc((size_t)MROWS*D_*4);
  unsigned short* hb      = (unsigned short*)alloc((size_t)MROWS*D_*2);
  unsigned short* qkvb    = (unsigned short*)alloc((size_t)MROWS*2304*2);
  unsigned short* ob      = (unsigned short*)alloc((size_t)MROWS*D_*2);
  unsigned short* ffb     = (unsigned short*)alloc((size_t)MROWS*3072*2);
  float*          pooled  = (float*)alloc((size_t)16*D_*4);

  // weight conversion / packing (bf16)
  k_pack_qkvw<<<2048, 256, 0, stream>>>(Wq, Wk, Wv, wqkv);
  k_pack_qkvb<<<(12*2304 + 255)/256, 256, 0, stream>>>(bq, bk, bv, bqkv);
  k_f2b<<<2048, 256, 0, stream>>>(Wo, wo, (long)12*768*768);
  k_f2b<<<2048, 256, 0, stream>>>(W1, w1, (long)12*3072*768);
  k_f2b<<<2048, 256, 0, stream>>>(W2, w2, (long)12*768*3072);
  k_patchw<<<2048, 256, 0, stream>>>(patch_w, wp);
  k_patches<<<2048, 256, 0, stream>>>(x, patches);

  // patch embed (+bias +pos) -> hf ; LN -> hf (in-place) + hb
  gemm_bt<<<72*6, 256, 0, stream>>>(patches, wp, patch_b, pos_emb,
                                    nullptr, hf, nullptr, MROWS, 768, KPAT, 0);
  k_ln<<<MROWS, 256, 0, stream>>>(hf, hb, ln_g, ln_b);

  for (int l = 0; l < 12; ++l){
    gemm_bt<<<72*18, 256, 0, stream>>>(hb, wqkv + (size_t)l*2304*768, bqkv + l*2304,
                                       nullptr, nullptr, nullptr, qkvb, MROWS, 2304, 768, 0);
    k_attn<<<192, 384, 0, stream>>>(qkvb, ob);
    gemm_bt<<<72*6, 256, 0, stream>>>(ob, wo + (size_t)l*768*768, bo + l*768,
                                      nullptr, hf, hf, hb, MROWS, 768, 768, 0);
    gemm_bt<<<72*24, 256, 0, stream>>>(hb, w1 + (size_t)l*3072*768, b1 + (size_t)l*3072,
                                       nullptr, nullptr, nullptr, ffb, MROWS, 3072, 768, 1);
    gemm_bt<<<72*6, 256, 0, stream>>>(ffb, w2 + (size_t)l*768*3072, b2 + l*768,
                                      nullptr, hf, hf, hb, MROWS, 768, 3072, 0);
  }
  k_pool<<<48, 256, 0, stream>>>(hf, pooled);
  k_fc<<<160, 64, 0, stream>>>(pooled, fc_w, fc_b, out);
}

// Round 4
// 4627.589 us; speedup vs baseline: 1.0361x; 1.0170x over previous
//
#include <hip/hip_runtime.h>
#include <stdint.h>
#include <stddef.h>

typedef __attribute__((ext_vector_type(8))) short short8;
typedef __attribute__((ext_vector_type(4))) short short4v;
typedef __attribute__((ext_vector_type(4))) float f32x4;

#define D_    768
#define HH    12
#define DHEAD 64
#define NP    576
#define BB    16
#define MROWS 9216      // BB*NP
#define KPAT  1216      // 1200 padded to multiple of 32
#define SCL   0.18033688011112042f   // 0.125 * log2(e)

static __device__ __forceinline__ unsigned short f2bf(float f){
  union { float f; unsigned int u; } v; v.f = f;
  unsigned int u = v.u;
  return (unsigned short)((u + 0x7FFFu + ((u >> 16) & 1u)) >> 16);
}

static __device__ __forceinline__ void gld16(const void* g, void* l){
  __builtin_amdgcn_global_load_lds((const __attribute__((address_space(1))) void*)g,
                                   (__attribute__((address_space(3))) void*)l,
                                   16, 0, 0);
}

// ---------------- GEMM: C[M,N] = A[M,K](bf16) @ W[N,K](bf16)^T + epilogue ----
// T1: bijective XCD chunking (gridDim.x % 8 == 0 for all uses).
// T2: 16B-slot XOR swizzle  p = s ^ ((s>>3)&3)  (2 lanes/bank-span = free).
// T3/T4: 3-buffer LDS, depth-2 prefetch, counted vmcnt(4), 1 barrier/K-step.
__global__ __launch_bounds__(256) void gemm_bt(
    const unsigned short* __restrict__ A,
    const unsigned short* __restrict__ W,
    const float* __restrict__ bias,
    const float* __restrict__ pos,   // optional [576,768]
    const float* res,                // optional [M,N] (may alias outf!)
    float* outf,                     // optional
    unsigned short* outb,            // optional
    int M, int N, int K, int relu)
{
  __shared__ unsigned short sA[3][128*32];
  __shared__ unsigned short sB[3][128*32];
  const int NB = N >> 7;
  const int nwg = (int)gridDim.x;
  int wid = (int)blockIdx.x;
  wid = (wid & 7) * (nwg >> 3) + (wid >> 3);   // XCD chunk: contiguous wids per XCD
  const int mb = wid / NB;
  const int nb = wid % NB;
  const int t = threadIdx.x;
  const int w = t >> 6, l = t & 63;
  const int m0 = mb << 7, n0 = nb << 7;

  const int srow = (w << 4) + (l >> 2);
  const int scb  = (l & 3) ^ ((l >> 3) & 3);   // write-side swizzled 16B-block idx
  const unsigned short* Ag = A + (size_t)(m0 + srow) * K + (scb << 3);
  const unsigned short* Wg = W + (size_t)(n0 + srow) * K + (scb << 3);
  const size_t g64 = (size_t)64 * K;

  const f32x4 zero = {0.f, 0.f, 0.f, 0.f};
  f32x4 acc[4][4];
  #pragma unroll
  for (int i = 0; i < 4; ++i)
    #pragma unroll
    for (int j = 0; j < 4; ++j) acc[i][j] = zero;

  const int KT = K >> 5;

  auto stage = [&](int kt){
    const int bf = kt % 3;
    const unsigned short* a0 = Ag + (size_t)kt * 32;
    const unsigned short* w0 = Wg + (size_t)kt * 32;
    gld16(a0,       &sA[bf][((w<<4) +  0)*32]);
    gld16(a0 + g64, &sA[bf][((w<<4) + 64)*32]);
    gld16(w0,       &sB[bf][((w<<4) +  0)*32]);
    gld16(w0 + g64, &sB[bf][((w<<4) + 64)*32]);
  };

  // prologue: stage tiles 0 and 1 (8 loads/wave outstanding)
  stage(0);
  stage(1);

  const int wr = w >> 1, wc = w & 1;
  const int fr = l & 15, fq = l >> 4;
  const int fsw = (fq ^ ((fr >> 1) & 3)) << 3;  // read-side swizzled k-block offset

  for (int kt = 0; kt < KT; ++kt){
    // RAW: own tile-kt loads landed (vmcnt<=4 leaves only tile kt+1 in flight);
    // WAR: own ds_reads of tile kt-1 drained (lgkmcnt 0); barrier -> all waves.
    if (kt == KT - 1) asm volatile("s_waitcnt vmcnt(0) lgkmcnt(0)" ::: "memory");
    else              asm volatile("s_waitcnt vmcnt(4) lgkmcnt(0)" ::: "memory");
    __builtin_amdgcn_s_barrier();
    asm volatile("" ::: "memory");
    if (kt + 2 < KT) stage(kt + 2);              // overwrites buf holding kt-1
    const int buf = kt % 3;
    short8 af[4], bv[4];
    #pragma unroll
    for (int mf = 0; mf < 4; ++mf)
      af[mf] = *(const short8*)&sA[buf][((wr<<6) + (mf<<4) + fr)*32 + fsw];
    #pragma unroll
    for (int nf = 0; nf < 4; ++nf)
      bv[nf] = *(const short8*)&sB[buf][((wc<<6) + (nf<<4) + fr)*32 + fsw];
    #pragma unroll
    for (int mf = 0; mf < 4; ++mf)
      #pragma unroll
      for (int nf = 0; nf < 4; ++nf)
        acc[mf][nf] = __builtin_amdgcn_mfma_f32_16x16x32_bf16(af[mf], bv[nf], acc[mf][nf], 0, 0, 0);
    asm volatile("" ::: "memory");
  }

  #pragma unroll
  for (int mf = 0; mf < 4; ++mf){
    #pragma unroll
    for (int nf = 0; nf < 4; ++nf){
      #pragma unroll
      for (int r = 0; r < 4; ++r){
        const int row = m0 + (wr<<6) + (mf<<4) + (fq<<2) + r;
        const int col = n0 + (wc<<6) + (nf<<4) + fr;
        float v = acc[mf][nf][r] + bias[col];
        if (pos)  v += pos[(size_t)(row % NP) * D_ + col];
        if (res)  v += res[(size_t)row * N + col];
        if (relu) v = fmaxf(v, 0.f);
        const size_t idx = (size_t)row * N + col;
        if (outf) outf[idx] = v;
        if (outb) outb[idx] = f2bf(v);
      }
    }
  }
}

// ---------------- fused attention, one (b,h) per block -----------------------
__global__ __launch_bounds__(384) void k_attn(const unsigned short* __restrict__ qkv,
                                              unsigned short* __restrict__ o)
{
  __shared__ unsigned short Kl[NP*DHEAD];      // [key][d], XOR-swizzled, 72KB
  __shared__ unsigned short Vt[DHEAD*NP];      // [d][key], XOR-swizzled, 72KB
  __shared__ unsigned short Pl[6][16*32];      // per-wave P tile
  const int bh = blockIdx.x;
  const int b = bh / HH, h = bh % HH;
  const unsigned short* base = qkv + (size_t)b * NP * 2304 + h * DHEAD;
  const int t = threadIdx.x;

  for (int cid = t; cid < 4608; cid += 384){   // stage K
    const int row = cid >> 3, g = cid & 7;
    short8 kv = *(const short8*)(base + 768 + (size_t)row * 2304 + (g << 3));
    const int off = (row << 7) + (((g << 4)) ^ ((row & 7) << 4));
    *(short8*)((char*)Kl + off) = kv;
  }
  for (int cid = t; cid < 4608; cid += 384){   // stage V transposed
    const int key = cid >> 3, g = cid & 7;
    short8 vv = *(const short8*)(base + 1536 + (size_t)key * 2304 + (g << 3));
    #pragma unroll
    for (int j = 0; j < 8; ++j){
      const int d = (g << 3) + j;
      const int off = (d * 1152 + (key << 1)) ^ ((d & 7) << 4);
      *(unsigned short*)((char*)Vt + off) = ((const unsigned short*)&vv)[j];
    }
  }
  __syncthreads();

  const int w = t >> 6, l = t & 63;
  const int fr = l & 15, fq = l >> 4;
  const f32x4 zero = {0.f, 0.f, 0.f, 0.f};

  for (int qi = 0; qi < 6; ++qi){
    const int q0 = (w + 6 * qi) << 4;
    const short8 qf0 = *(const short8*)(base + (size_t)(q0 + fr) * 2304 + (fq << 3));
    const short8 qf1 = *(const short8*)(base + (size_t)(q0 + fr) * 2304 + 32 + (fq << 3));
    float m = -1e30f, lsum = 0.f;
    f32x4 oa[4];
    #pragma unroll
    for (int nf = 0; nf < 4; ++nf) oa[nf] = zero;

    for (int kc = 0; kc < 18; ++kc){
      const int key0 = kc << 5;
      f32x4 s0 = zero, s1 = zero;
      {
        const int r0 = key0 + fr, r1 = key0 + 16 + fr;
        const int sw0 = (r0 & 7) << 4, sw1 = (r1 & 7) << 4;
        short8 k00 = *(const short8*)((char*)Kl + (r0 << 7) + (((fq << 4)     ) ^ sw0));
        short8 k01 = *(const short8*)((char*)Kl + (r0 << 7) + (((fq << 4) + 64) ^ sw0));
        short8 k10 = *(const short8*)((char*)Kl + (r1 << 7) + (((fq << 4)     ) ^ sw1));
        short8 k11 = *(const short8*)((char*)Kl + (r1 << 7) + (((fq << 4) + 64) ^ sw1));
        s0 = __builtin_amdgcn_mfma_f32_16x16x32_bf16(k00, qf0, s0, 0, 0, 0);
        s0 = __builtin_amdgcn_mfma_f32_16x16x32_bf16(k01, qf1, s0, 0, 0, 0);
        s1 = __builtin_amdgcn_mfma_f32_16x16x32_bf16(k10, qf0, s1, 0, 0, 0);
        s1 = __builtin_amdgcn_mfma_f32_16x16x32_bf16(k11, qf1, s1, 0, 0, 0);
      }
      // S^T[key][q]: lane holds keys {fq*4+r} and {16+fq*4+r} for q = fr
      float mx = fmaxf(fmaxf(fmaxf(s0[0], s0[1]), fmaxf(s0[2], s0[3])),
                       fmaxf(fmaxf(s1[0], s1[1]), fmaxf(s1[2], s1[3])));
      mx = fmaxf(mx, __shfl_xor(mx, 16));
      mx = fmaxf(mx, __shfl_xor(mx, 32));
      const float mb = mx * SCL;
      const float mn = fmaxf(m, mb);
      const float fc = exp2f(m - mn);
      const float p0 = exp2f(s0[0]*SCL - mn), p1 = exp2f(s0[1]*SCL - mn);
      const float p2 = exp2f(s0[2]*SCL - mn), p3 = exp2f(s0[3]*SCL - mn);
      const float p4 = exp2f(s1[0]*SCL - mn), p5 = exp2f(s1[1]*SCL - mn);
      const float p6 = exp2f(s1[2]*SCL - mn), p7 = exp2f(s1[3]*SCL - mn);
      float ps = ((p0+p1)+(p2+p3)) + ((p4+p5)+(p6+p7));
      ps += __shfl_xor(ps, 16);
      ps += __shfl_xor(ps, 32);
      lsum = lsum * fc + ps;
      m = mn;
      if (!__all(fc == 1.0f)){
        const float fA = __shfl(fc, (fq<<2) + 0);
        const float fB = __shfl(fc, (fq<<2) + 1);
        const float fC = __shfl(fc, (fq<<2) + 2);
        const float fD = __shfl(fc, (fq<<2) + 3);
        #pragma unroll
        for (int nf = 0; nf < 4; ++nf){
          oa[nf][0] *= fA; oa[nf][1] *= fB; oa[nf][2] *= fC; oa[nf][3] *= fD;
        }
      }
      const short4v pv0 = { (short)f2bf(p0), (short)f2bf(p1), (short)f2bf(p2), (short)f2bf(p3) };
      const short4v pv1 = { (short)f2bf(p4), (short)f2bf(p5), (short)f2bf(p6), (short)f2bf(p7) };
      *(short4v*)&Pl[w][(fr<<5) + (fq<<2)]      = pv0;
      *(short4v*)&Pl[w][(fr<<5) + 16 + (fq<<2)] = pv1;
      asm volatile("" ::: "memory");
      const short8 pa = *(const short8*)&Pl[w][(fr<<5) + (fq<<3)];
      #pragma unroll
      for (int nf = 0; nf < 4; ++nf){
        const int d = (nf << 4) + fr;
        const int off = (d * 1152 + ((key0 + (fq << 3)) << 1)) ^ ((d & 7) << 4);
        const short8 vf = *(const short8*)((char*)Vt + off);
        oa[nf] = __builtin_amdgcn_mfma_f32_16x16x32_bf16(pa, vf, oa[nf], 0, 0, 0);
      }
    }
    const float rl = 1.f / lsum;
    const float rA = __shfl(rl, (fq<<2)+0), rB = __shfl(rl, (fq<<2)+1);
    const float rC = __shfl(rl, (fq<<2)+2), rD = __shfl(rl, (fq<<2)+3);
    #pragma unroll
    for (int nf = 0; nf < 4; ++nf){
      const int col = h * DHEAD + (nf << 4) + fr;
      const size_t r0 = (size_t)(b * NP + q0 + (fq << 2));
      o[(r0 + 0) * D_ + col] = f2bf(oa[nf][0] * rA);
      o[(r0 + 1) * D_ + col] = f2bf(oa[nf][1] * rB);
      o[(r0 + 2) * D_ + col] = f2bf(oa[nf][2] * rC);
      o[(r0 + 3) * D_ + col] = f2bf(oa[nf][3] * rD);
    }
  }
}

// ---------------- small kernels ----------------------------------------------
__global__ void k_f2b(const float* __restrict__ s, unsigned short* __restrict__ d, long n){
  long i = (long)blockIdx.x * blockDim.x + threadIdx.x;
  const long st = (long)gridDim.x * blockDim.x;
  for (; i < n; i += st) d[i] = f2bf(s[i]);
}

__global__ void k_pack_qkvw(const float* __restrict__ Wq, const float* __restrict__ Wk,
                            const float* __restrict__ Wv, unsigned short* __restrict__ dst){
  const long n = (long)12 * 2304 * 768;
  long i = (long)blockIdx.x * blockDim.x + threadIdx.x;
  const long st = (long)gridDim.x * blockDim.x;
  for (; i < n; i += st){
    const int lay = (int)(i / (2304 * 768));
    const int rem = (int)(i % (2304 * 768));
    const int r = rem / 768, k = rem % 768;
    // NOTE: 768 is NOT pow2 — must use real modulo, not &767 (round-1 bug)
    const float* s = (r < 768) ? Wq : ((r < 1536) ? Wk : Wv);
    const int rr = (r < 768) ? r : ((r < 1536) ? r - 768 : r - 1536);
    dst[i] = f2bf(s[(size_t)lay * 589824 + (size_t)rr * 768 + k]);
  }
}

__global__ void k_pack_qkvb(const float* __restrict__ bq, const float* __restrict__ bk,
                            const float* __restrict__ bv, float* __restrict__ dst){
  const int i = blockIdx.x * 256 + threadIdx.x;
  if (i >= 12 * 2304) return;
  const int lay = i / 2304, r = i % 2304;
  const float* s = (r < 768) ? bq : ((r < 1536) ? bk : bv);
  const int rr = (r < 768) ? r : ((r < 1536) ? r - 768 : r - 1536);
  dst[i] = s[lay * 768 + rr];
}

__global__ void k_patchw(const float* __restrict__ s, unsigned short* __restrict__ d){
  const long n = (long)768 * KPAT;
  long i = (long)blockIdx.x * blockDim.x + threadIdx.x;
  const long st = (long)gridDim.x * blockDim.x;
  for (; i < n; i += st){
    const int r = (int)(i / KPAT), k = (int)(i % KPAT);
    d[i] = (k < 1200) ? f2bf(s[(size_t)r * 1200 + k]) : (unsigned short)0;
  }
}

__global__ void k_patches(const float* __restrict__ x, unsigned short* __restrict__ d){
  const long n = (long)MROWS * KPAT;
  long i = (long)blockIdx.x * blockDim.x + threadIdx.x;
  const long st = (long)gridDim.x * blockDim.x;
  for (; i < n; i += st){
    const int mrow = (int)(i / KPAT), k = (int)(i % KPAT);
    unsigned short v = 0;
    if (k < 1200){
      const int c = k / 400, rem = k % 400, py = rem / 20, px = rem % 20;
      const int b = mrow / NP, pn = mrow % NP, hp = pn / 18, wp = pn % 18;
      v = f2bf(x[(((size_t)b * 3 + c) * 640 + hp * 20 + py) * 360 + wp * 20 + px]);
    }
    d[i] = v;
  }
}

__global__ __launch_bounds__(256) void k_ln(float* h, unsigned short* hb,
                                            const float* __restrict__ g,
                                            const float* __restrict__ bt){
  const int r = blockIdx.x, t = threadIdx.x;
  const size_t base = (size_t)r * D_;
  const float x0 = h[base + t], x1 = h[base + t + 256], x2 = h[base + t + 512];
  float s = x0 + x1 + x2;
  #pragma unroll
  for (int o = 1; o < 64; o <<= 1) s += __shfl_xor(s, o);
  __shared__ float red[8];
  const int w = t >> 6, l = t & 63;
  if (l == 0) red[w] = s;
  __syncthreads();
  const float mu = (red[0] + red[1] + red[2] + red[3]) * (1.f / 768.f);
  const float d0 = x0 - mu, d1 = x1 - mu, d2 = x2 - mu;
  float v = d0*d0 + d1*d1 + d2*d2;
  #pragma unroll
  for (int o = 1; o < 64; o <<= 1) v += __shfl_xor(v, o);
  if (l == 0) red[4 + w] = v;
  __syncthreads();
  const float var = (red[4] + red[5] + red[6] + red[7]) * (1.f / 768.f);
  const float rs = rsqrtf(var + 1e-5f);
  const float y0 = d0 * rs * g[t]       + bt[t];
  const float y1 = d1 * rs * g[t + 256] + bt[t + 256];
  const float y2 = d2 * rs * g[t + 512] + bt[t + 512];
  h[base + t] = y0; h[base + t + 256] = y1; h[base + t + 512] = y2;
  hb[base + t] = f2bf(y0); hb[base + t + 256] = f2bf(y1); hb[base + t + 512] = f2bf(y2);
}

__global__ void k_pool(const float* __restrict__ h, float* __restrict__ p){
  const int i = blockIdx.x * 256 + threadIdx.x;   // 12288
  const int b = i / D_, c = i % D_;
  const float* base = h + (size_t)b * NP * D_ + c;
  float s = 0.f;
  for (int n = 0; n < NP; ++n) s += base[(size_t)n * D_];
  p[i] = s * (1.f / 576.f);
}

__global__ __launch_bounds__(64) void k_fc(const float* __restrict__ p, const float* __restrict__ w,
                                           const float* __restrict__ bias, float* __restrict__ out){
  const int oi = blockIdx.x;                       // 160
  const int b = oi / 10, j = oi % 10;
  const int l = threadIdx.x;
  float s = 0.f;
  for (int c = l; c < D_; c += 64) s += p[b * D_ + c] * w[j * D_ + c];
  #pragma unroll
  for (int o = 1; o < 64; o <<= 1) s += __shfl_xor(s, o);
  if (l == 0) out[oi] = s + bias[j];
}

// ---------------- launch ------------------------------------------------------
extern "C" void kernel_launch(void* const* d_in, const int* in_sizes, int n_in,
                              void* d_out, int out_size, void* d_ws, size_t ws_size,
                              hipStream_t stream)
{
  const float* x       = (const float*)d_in[0];
  const float* patch_w = (const float*)d_in[1];
  const float* patch_b = (const float*)d_in[2];
  const float* pos_emb = (const float*)d_in[3];
  const float* ln_g    = (const float*)d_in[4];
  const float* ln_b    = (const float*)d_in[5];
  const float* Wq      = (const float*)d_in[6];
  const float* bq      = (const float*)d_in[7];
  const float* Wk      = (const float*)d_in[8];
  const float* bk      = (const float*)d_in[9];
  const float* Wv      = (const float*)d_in[10];
  const float* bv      = (const float*)d_in[11];
  const float* Wo      = (const float*)d_in[12];
  const float* bo      = (const float*)d_in[13];
  const float* W1      = (const float*)d_in[14];
  const float* b1      = (const float*)d_in[15];
  const float* W2      = (const float*)d_in[16];
  const float* b2      = (const float*)d_in[17];
  const float* fc_w    = (const float*)d_in[18];
  const float* fc_b    = (const float*)d_in[19];
  float* out = (float*)d_out;
  (void)in_sizes; (void)n_in; (void)out_size; (void)ws_size;

  char* ws = (char*)d_ws;
  size_t off = 0;
  auto alloc = [&](size_t bytes) -> char* {
    char* p = ws + off;
    off += (bytes + 255) & ~(size_t)255;
    return p;
  };
  unsigned short* wqkv    = (unsigned short*)alloc((size_t)12*2304*768*2);
  unsigned short* wo      = (unsigned short*)alloc((size_t)12*768*768*2);
  unsigned short* w1      = (unsigned short*)alloc((size_t)12*3072*768*2);
  unsigned short* w2      = (unsigned short*)alloc((size_t)12*768*3072*2);
  unsigned short* wp      = (unsigned short*)alloc((size_t)768*KPAT*2);
  float*          bqkv    = (float*)alloc((size_t)12*2304*4);
  unsigned short* patches = (unsigned short*)alloc((size_t)MROWS*KPAT*2);
  float*          hf      = (float*)alloc((size_t)MROWS*D_*4);
  unsigned short* hb      = (unsigned short*)alloc((size_t)MROWS*D_*2);
  unsigned short* qkvb    = (unsigned short*)alloc((size_t)MROWS*2304*2);
  unsigned short* ob      = (unsigned short*)alloc((size_t)MROWS*D_*2);
  unsigned short* ffb     = (unsigned short*)alloc((size_t)MROWS*3072*2);
  float*          pooled  = (float*)alloc((size_t)16*D_*4);

  // weight conversion / packing (bf16)
  k_pack_qkvw<<<2048, 256, 0, stream>>>(Wq, Wk, Wv, wqkv);
  k_pack_qkvb<<<(12*2304 + 255)/256, 256, 0, stream>>>(bq, bk, bv, bqkv);
  k_f2b<<<2048, 256, 0, stream>>>(Wo, wo, (long)12*768*768);
  k_f2b<<<2048, 256, 0, stream>>>(W1, w1, (long)12*3072*768);
  k_f2b<<<2048, 256, 0, stream>>>(W2, w2, (long)12*768*3072);
  k_patchw<<<2048, 256, 0, stream>>>(patch_w, wp);
  k_patches<<<2048, 256, 0, stream>>>(x, patches);

  // patch embed (+bias +pos) -> hf ; LN -> hf (in-place) + hb
  gemm_bt<<<72*6, 256, 0, stream>>>(patches, wp, patch_b, pos_emb,
                                    nullptr, hf, nullptr, MROWS, 768, KPAT, 0);
  k_ln<<<MROWS, 256, 0, stream>>>(hf, hb, ln_g, ln_b);

  for (int l = 0; l < 12; ++l){
    gemm_bt<<<72*18, 256, 0, stream>>>(hb, wqkv + (size_t)l*2304*768, bqkv + l*2304,
                                       nullptr, nullptr, nullptr, qkvb, MROWS, 2304, 768, 0);
    k_attn<<<192, 384, 0, stream>>>(qkvb, ob);
    gemm_bt<<<72*6, 256, 0, stream>>>(ob, wo + (size_t)l*768*768, bo + l*768,
                                      nullptr, hf, hf, hb, MROWS, 768, 768, 0);
    gemm_bt<<<72*24, 256, 0, stream>>>(hb, w1 + (size_t)l*3072*768, b1 + (size_t)l*3072,
                                       nullptr, nullptr, nullptr, ffb, MROWS, 3072, 768, 1);
    gemm_bt<<<72*6, 256, 0, stream>>>(ffb, w2 + (size_t)l*768*3072, b2 + l*768,
                                      nullptr, hf, hf, hb, MROWS, 768, 3072, 0);
  }
  k_pool<<<48, 256, 0, stream>>>(hf, pooled);
  k_fc<<<160, 64, 0, stream>>>(pooled, fc_w, fc_b, out);
}

// Round 5
// 4258.212 us; speedup vs baseline: 1.1259x; 1.0867x over previous
//
#include <hip/hip_runtime.h>
#include <stdint.h>
#include <stddef.h>

typedef __attribute__((ext_vector_type(8))) short short8;
typedef __attribute__((ext_vector_type(4))) float f32x4;

#define D_    768
#define HH    12
#define DHEAD 64
#define NP    576
#define BB    16
#define MROWS 9216      // BB*NP
#define KPAT  1216      // 1200 padded to multiple of 32
#define SCL   0.18033688011112042f   // 0.125 * log2(e)

static __device__ __forceinline__ unsigned short f2bf(float f){
  union { float f; unsigned int u; } v; v.f = f;
  unsigned int u = v.u;
  return (unsigned short)((u + 0x7FFFu + ((u >> 16) & 1u)) >> 16);
}

static __device__ __forceinline__ void gld16(const void* g, void* l){
  __builtin_amdgcn_global_load_lds((const __attribute__((address_space(1))) void*)g,
                                   (__attribute__((address_space(3))) void*)l,
                                   16, 0, 0);
}

// ---------------- GEMM: C[M,N] = A[M,K](bf16) @ W[N,K](bf16)^T + epilogue ----
// T1: bijective XCD chunking (gridDim.x % 8 == 0 for all uses).
// T2: 16B-slot XOR swizzle  p = s ^ ((s>>3)&3).
// T3/T4: 3-buffer LDS, depth-2 prefetch, counted vmcnt(4), 1 barrier/K-step.
__global__ __launch_bounds__(256) void gemm_bt(
    const unsigned short* __restrict__ A,
    const unsigned short* __restrict__ W,
    const float* __restrict__ bias,
    const float* __restrict__ pos,   // optional [576,768]
    const float* res,                // optional [M,N] (may alias outf!)
    float* outf,                     // optional
    unsigned short* outb,            // optional
    int M, int N, int K, int relu)
{
  __shared__ unsigned short sA[3][128*32];
  __shared__ unsigned short sB[3][128*32];
  const int NB = N >> 7;
  const int nwg = (int)gridDim.x;
  int wid = (int)blockIdx.x;
  wid = (wid & 7) * (nwg >> 3) + (wid >> 3);   // XCD chunk: contiguous wids per XCD
  const int mb = wid / NB;
  const int nb = wid % NB;
  const int t = threadIdx.x;
  const int w = t >> 6, l = t & 63;
  const int m0 = mb << 7, n0 = nb << 7;

  const int srow = (w << 4) + (l >> 2);
  const int scb  = (l & 3) ^ ((l >> 3) & 3);   // write-side swizzled 16B-block idx
  const unsigned short* Ag = A + (size_t)(m0 + srow) * K + (scb << 3);
  const unsigned short* Wg = W + (size_t)(n0 + srow) * K + (scb << 3);
  const size_t g64 = (size_t)64 * K;

  const f32x4 zero = {0.f, 0.f, 0.f, 0.f};
  f32x4 acc[4][4];
  #pragma unroll
  for (int i = 0; i < 4; ++i)
    #pragma unroll
    for (int j = 0; j < 4; ++j) acc[i][j] = zero;

  const int KT = K >> 5;

  auto stage = [&](int kt){
    const int bf = kt % 3;
    const unsigned short* a0 = Ag + (size_t)kt * 32;
    const unsigned short* w0 = Wg + (size_t)kt * 32;
    gld16(a0,       &sA[bf][((w<<4) +  0)*32]);
    gld16(a0 + g64, &sA[bf][((w<<4) + 64)*32]);
    gld16(w0,       &sB[bf][((w<<4) +  0)*32]);
    gld16(w0 + g64, &sB[bf][((w<<4) + 64)*32]);
  };

  stage(0);
  stage(1);

  const int wr = w >> 1, wc = w & 1;
  const int fr = l & 15, fq = l >> 4;
  const int fsw = (fq ^ ((fr >> 1) & 3)) << 3;  // read-side swizzled k-block offset

  for (int kt = 0; kt < KT; ++kt){
    if (kt == KT - 1) asm volatile("s_waitcnt vmcnt(0) lgkmcnt(0)" ::: "memory");
    else              asm volatile("s_waitcnt vmcnt(4) lgkmcnt(0)" ::: "memory");
    __builtin_amdgcn_s_barrier();
    asm volatile("" ::: "memory");
    if (kt + 2 < KT) stage(kt + 2);              // overwrites buf holding kt-1
    const int buf = kt % 3;
    short8 af[4], bv[4];
    #pragma unroll
    for (int mf = 0; mf < 4; ++mf)
      af[mf] = *(const short8*)&sA[buf][((wr<<6) + (mf<<4) + fr)*32 + fsw];
    #pragma unroll
    for (int nf = 0; nf < 4; ++nf)
      bv[nf] = *(const short8*)&sB[buf][((wc<<6) + (nf<<4) + fr)*32 + fsw];
    #pragma unroll
    for (int mf = 0; mf < 4; ++mf)
      #pragma unroll
      for (int nf = 0; nf < 4; ++nf)
        acc[mf][nf] = __builtin_amdgcn_mfma_f32_16x16x32_bf16(af[mf], bv[nf], acc[mf][nf], 0, 0, 0);
    asm volatile("" ::: "memory");
  }

  #pragma unroll
  for (int mf = 0; mf < 4; ++mf){
    #pragma unroll
    for (int nf = 0; nf < 4; ++nf){
      #pragma unroll
      for (int r = 0; r < 4; ++r){
        const int row = m0 + (wr<<6) + (mf<<4) + (fq<<2) + r;
        const int col = n0 + (wc<<6) + (nf<<4) + fr;
        float v = acc[mf][nf][r] + bias[col];
        if (pos)  v += pos[(size_t)(row % NP) * D_ + col];
        if (res)  v += res[(size_t)row * N + col];
        if (relu) v = fmaxf(v, 0.f);
        const size_t idx = (size_t)row * N + col;
        if (outf) outf[idx] = v;
        if (outb) outb[idx] = f2bf(v);
      }
    }
  }
}

// ---------------- fused attention v2 ------------------------------------------
// 576 blocks = (b,h) x 3 q-splits (bh-adjacent wids -> same XCD for K/V L2 reuse)
// 384 threads (6 waves, 2 q-tiles each). K/V double-buffered in 32-key tiles.
// LDS 24.6 KB -> ~2 blocks/CU (12 waves). In-register P regroup (cvt_pk+shfl).
__global__ __launch_bounds__(384) void k_attn(const unsigned short* __restrict__ qkv,
                                              unsigned short* __restrict__ o)
{
  __shared__ unsigned short Kl[2][32*64];   // [key][d-slot], source-preswizzled
  __shared__ unsigned short Vt[2][64*64];   // [d][key-slot], swizzled rows (128B)
  const int nwg = (int)gridDim.x;           // 576
  int wid = (int)blockIdx.x;
  wid = (wid & 7) * (nwg >> 3) + (wid >> 3);
  const int bh = wid / 3, qs = wid % 3;
  const int b = bh / HH, h = bh % HH;
  const unsigned short* base = qkv + (size_t)b * NP * 2304 + h * DHEAD;
  const int t = threadIdx.x;
  const int w = t >> 6, l = t & 63;
  const int fr = l & 15, fq = l >> 4;
  const int sg = l & 7;                     // staging d-chunk / K slot
  const int sr = ((w & 3) << 3) + (l >> 3); // staging key row 0..31 (waves 0-3)
  const bool stw = (t < 256);

  // persistent Q fragments (2 q-tiles per wave)
  short8 qfa[2], qfb[2];
  #pragma unroll
  for (int qt = 0; qt < 2; ++qt){
    const size_t qrow = (size_t)(qs*192 + (qt*6 + w)*16 + fr);
    qfa[qt] = *(const short8*)(base + qrow*2304 + (fq<<3));
    qfb[qt] = *(const short8*)(base + qrow*2304 + 32 + (fq<<3));
  }

  const f32x4 zero = {0.f, 0.f, 0.f, 0.f};
  float mx_[2] = {-1e30f, -1e30f};
  float ls_[2] = {0.f, 0.f};
  f32x4 oa[2][4];
  #pragma unroll
  for (int qt = 0; qt < 2; ++qt)
    #pragma unroll
    for (int nf = 0; nf < 4; ++nf) oa[qt][nf] = zero;

  // prologue: stage tile 0
  if (stw){
    gld16(base + 768 + (size_t)sr*2304 + ((sg ^ (sr&7))<<3), &Kl[0][(w&3)*512]);
    short8 vv = *(const short8*)(base + 1536 + (size_t)sr*2304 + (sg<<3));
    asm volatile("s_waitcnt vmcnt(0)" ::: "memory");
    #pragma unroll
    for (int j = 0; j < 8; ++j){
      const int d = sg*8 + j;
      const int off = (d<<7) + ((((sr>>3) ^ j ^ sg) & 7) << 4) + ((sr&7)<<1);
      *(unsigned short*)((char*)&Vt[0][0] + off) = ((const unsigned short*)&vv)[j];
    }
  }
  __syncthreads();

  for (int kt = 0; kt < 18; ++kt){
    const int buf = kt & 1;
    short8 vv;
    const bool st = stw && (kt < 17);
    if (st){
      const int key = (kt+1)*32 + sr;
      gld16(base + 768 + (size_t)key*2304 + ((sg ^ (sr&7))<<3), &Kl[buf^1][(w&3)*512]);
      vv = *(const short8*)(base + 1536 + (size_t)key*2304 + (sg<<3));
    }

    // K fragments (shared by both q-tiles)
    const char* kb = (const char*)&Kl[buf][0];
    const int r0 = fr, r1 = 16 + fr;
    const short8 k00 = *(const short8*)(kb + (r0<<7) + (((fq    ) ^ (r0&7))<<4));
    const short8 k01 = *(const short8*)(kb + (r0<<7) + (((4+fq ) ^ (r0&7))<<4));
    const short8 k10 = *(const short8*)(kb + (r1<<7) + (((fq    ) ^ (r1&7))<<4));
    const short8 k11 = *(const short8*)(kb + (r1<<7) + (((4+fq ) ^ (r1&7))<<4));
    const char* vb = (const char*)&Vt[buf][0];

    #pragma unroll
    for (int qt = 0; qt < 2; ++qt){
      f32x4 s0 = zero, s1 = zero;
      s0 = __builtin_amdgcn_mfma_f32_16x16x32_bf16(k00, qfa[qt], s0, 0, 0, 0);
      s0 = __builtin_amdgcn_mfma_f32_16x16x32_bf16(k01, qfb[qt], s0, 0, 0, 0);
      s1 = __builtin_amdgcn_mfma_f32_16x16x32_bf16(k10, qfa[qt], s1, 0, 0, 0);
      s1 = __builtin_amdgcn_mfma_f32_16x16x32_bf16(k11, qfb[qt], s1, 0, 0, 0);
      // lane holds S^T[key0 + fq*4 + r][q=fr] (s0) and +16 (s1)
      float mx = fmaxf(fmaxf(fmaxf(s0[0], s0[1]), fmaxf(s0[2], s0[3])),
                       fmaxf(fmaxf(s1[0], s1[1]), fmaxf(s1[2], s1[3])));
      mx = fmaxf(mx, __shfl_xor(mx, 16));
      mx = fmaxf(mx, __shfl_xor(mx, 32));
      const float mn = fmaxf(mx_[qt], mx * SCL);
      const float fc = exp2f(mx_[qt] - mn);
      const float p0 = exp2f(s0[0]*SCL - mn), p1 = exp2f(s0[1]*SCL - mn);
      const float p2 = exp2f(s0[2]*SCL - mn), p3 = exp2f(s0[3]*SCL - mn);
      const float p4 = exp2f(s1[0]*SCL - mn), p5 = exp2f(s1[1]*SCL - mn);
      const float p6 = exp2f(s1[2]*SCL - mn), p7 = exp2f(s1[3]*SCL - mn);
      float ps = ((p0+p1)+(p2+p3)) + ((p4+p5)+(p6+p7));
      ps += __shfl_xor(ps, 16);
      ps += __shfl_xor(ps, 32);
      ls_[qt] = ls_[qt] * fc + ps;
      mx_[qt] = mn;
      if (!__all(fc == 1.0f)){
        const float fA = __shfl(fc, (fq<<2) + 0);
        const float fB = __shfl(fc, (fq<<2) + 1);
        const float fC = __shfl(fc, (fq<<2) + 2);
        const float fD = __shfl(fc, (fq<<2) + 3);
        #pragma unroll
        for (int nf = 0; nf < 4; ++nf){
          oa[qt][nf][0] *= fA; oa[qt][nf][1] *= fB;
          oa[qt][nf][2] *= fC; oa[qt][nf][3] *= fD;
        }
      }
      // in-register P regroup -> PV A-fragment (keys fq*8..fq*8+7 for q=fr)
      unsigned d0, d1, d2, d3;
      asm("v_cvt_pk_bf16_f32 %0, %1, %2" : "=v"(d0) : "v"(p0), "v"(p1));
      asm("v_cvt_pk_bf16_f32 %0, %1, %2" : "=v"(d1) : "v"(p2), "v"(p3));
      asm("v_cvt_pk_bf16_f32 %0, %1, %2" : "=v"(d2) : "v"(p4), "v"(p5));
      asm("v_cvt_pk_bf16_f32 %0, %1, %2" : "=v"(d3) : "v"(p6), "v"(p7));
      const int srcA = fr + ((fq & 1) << 5);
      const unsigned a0 = (unsigned)__shfl((int)d0, srcA);
      const unsigned a1 = (unsigned)__shfl((int)d1, srcA);
      const unsigned a2 = (unsigned)__shfl((int)d2, srcA);
      const unsigned a3 = (unsigned)__shfl((int)d3, srcA);
      const unsigned b0 = (unsigned)__shfl((int)d0, srcA + 16);
      const unsigned b1 = (unsigned)__shfl((int)d1, srcA + 16);
      const unsigned b2 = (unsigned)__shfl((int)d2, srcA + 16);
      const unsigned b3 = (unsigned)__shfl((int)d3, srcA + 16);
      const bool hi = fq >= 2;
      union { unsigned u[4]; short8 v; } pk;
      pk.u[0] = hi ? a2 : a0;
      pk.u[1] = hi ? a3 : a1;
      pk.u[2] = hi ? b2 : b0;
      pk.u[3] = hi ? b3 : b1;
      const short8 pa = pk.v;
      #pragma unroll
      for (int nf = 0; nf < 4; ++nf){
        const int d = (nf<<4) + fr;
        const short8 vf = *(const short8*)(vb + (d<<7) + (((fq ^ (d&7) ^ (d>>3)) & 7)<<4));
        oa[qt][nf] = __builtin_amdgcn_mfma_f32_16x16x32_bf16(pa, vf, oa[qt][nf], 0, 0, 0);
      }
    }

    if (st){
      asm volatile("s_waitcnt vmcnt(0)" ::: "memory");   // vv + K gld16 landed
      #pragma unroll
      for (int j = 0; j < 8; ++j){
        const int d = sg*8 + j;
        const int off = (d<<7) + ((((sr>>3) ^ j ^ sg) & 7) << 4) + ((sr&7)<<1);
        *(unsigned short*)((char*)&Vt[buf^1][0] + off) = ((const unsigned short*)&vv)[j];
      }
    }
    __syncthreads();
  }

  #pragma unroll
  for (int qt = 0; qt < 2; ++qt){
    const float rl = 1.f / ls_[qt];
    const float rA = __shfl(rl, (fq<<2)+0), rB = __shfl(rl, (fq<<2)+1);
    const float rC = __shfl(rl, (fq<<2)+2), rD = __shfl(rl, (fq<<2)+3);
    const size_t r0 = (size_t)(b*NP + qs*192 + (qt*6 + w)*16 + (fq<<2));
    #pragma unroll
    for (int nf = 0; nf < 4; ++nf){
      const int col = h*DHEAD + (nf<<4) + fr;
      o[(r0 + 0)*D_ + col] = f2bf(oa[qt][nf][0] * rA);
      o[(r0 + 1)*D_ + col] = f2bf(oa[qt][nf][1] * rB);
      o[(r0 + 2)*D_ + col] = f2bf(oa[qt][nf][2] * rC);
      o[(r0 + 3)*D_ + col] = f2bf(oa[qt][nf][3] * rD);
    }
  }
}

// ---------------- small kernels ----------------------------------------------
__global__ void k_f2b(const float* __restrict__ s, unsigned short* __restrict__ d, long n){
  long i = (long)blockIdx.x * blockDim.x + threadIdx.x;
  const long st = (long)gridDim.x * blockDim.x;
  for (; i < n; i += st) d[i] = f2bf(s[i]);
}

__global__ void k_pack_qkvw(const float* __restrict__ Wq, const float* __restrict__ Wk,
                            const float* __restrict__ Wv, unsigned short* __restrict__ dst){
  const long n = (long)12 * 2304 * 768;
  long i = (long)blockIdx.x * blockDim.x + threadIdx.x;
  const long st = (long)gridDim.x * blockDim.x;
  for (; i < n; i += st){
    const int lay = (int)(i / (2304 * 768));
    const int rem = (int)(i % (2304 * 768));
    const int r = rem / 768, k = rem % 768;
    const float* s = (r < 768) ? Wq : ((r < 1536) ? Wk : Wv);
    const int rr = (r < 768) ? r : ((r < 1536) ? r - 768 : r - 1536);
    dst[i] = f2bf(s[(size_t)lay * 589824 + (size_t)rr * 768 + k]);
  }
}

__global__ void k_pack_qkvb(const float* __restrict__ bq, const float* __restrict__ bk,
                            const float* __restrict__ bv, float* __restrict__ dst){
  const int i = blockIdx.x * 256 + threadIdx.x;
  if (i >= 12 * 2304) return;
  const int lay = i / 2304, r = i % 2304;
  const float* s = (r < 768) ? bq : ((r < 1536) ? bk : bv);
  const int rr = (r < 768) ? r : ((r < 1536) ? r - 768 : r - 1536);
  dst[i] = s[lay * 768 + rr];
}

__global__ void k_patchw(const float* __restrict__ s, unsigned short* __restrict__ d){
  const long n = (long)768 * KPAT;
  long i = (long)blockIdx.x * blockDim.x + threadIdx.x;
  const long st = (long)gridDim.x * blockDim.x;
  for (; i < n; i += st){
    const int r = (int)(i / KPAT), k = (int)(i % KPAT);
    d[i] = (k < 1200) ? f2bf(s[(size_t)r * 1200 + k]) : (unsigned short)0;
  }
}

__global__ void k_patches(const float* __restrict__ x, unsigned short* __restrict__ d){
  const long n = (long)MROWS * KPAT;
  long i = (long)blockIdx.x * blockDim.x + threadIdx.x;
  const long st = (long)gridDim.x * blockDim.x;
  for (; i < n; i += st){
    const int mrow = (int)(i / KPAT), k = (int)(i % KPAT);
    unsigned short v = 0;
    if (k < 1200){
      const int c = k / 400, rem = k % 400, py = rem / 20, px = rem % 20;
      const int b = mrow / NP, pn = mrow % NP, hp = pn / 18, wp = pn % 18;
      v = f2bf(x[(((size_t)b * 3 + c) * 640 + hp * 20 + py) * 360 + wp * 20 + px]);
    }
    d[i] = v;
  }
}

__global__ __launch_bounds__(256) void k_ln(float* h, unsigned short* hb,
                                            const float* __restrict__ g,
                                            const float* __restrict__ bt){
  const int r = blockIdx.x, t = threadIdx.x;
  const size_t base = (size_t)r * D_;
  const float x0 = h[base + t], x1 = h[base + t + 256], x2 = h[base + t + 512];
  float s = x0 + x1 + x2;
  #pragma unroll
  for (int o = 1; o < 64; o <<= 1) s += __shfl_xor(s, o);
  __shared__ float red[8];
  const int w = t >> 6, l = t & 63;
  if (l == 0) red[w] = s;
  __syncthreads();
  const float mu = (red[0] + red[1] + red[2] + red[3]) * (1.f / 768.f);
  const float d0 = x0 - mu, d1 = x1 - mu, d2 = x2 - mu;
  float v = d0*d0 + d1*d1 + d2*d2;
  #pragma unroll
  for (int o = 1; o < 64; o <<= 1) v += __shfl_xor(v, o);
  if (l == 0) red[4 + w] = v;
  __syncthreads();
  const float var = (red[4] + red[5] + red[6] + red[7]) * (1.f / 768.f);
  const float rs = rsqrtf(var + 1e-5f);
  const float y0 = d0 * rs * g[t]       + bt[t];
  const float y1 = d1 * rs * g[t + 256] + bt[t + 256];
  const float y2 = d2 * rs * g[t + 512] + bt[t + 512];
  h[base + t] = y0; h[base + t + 256] = y1; h[base + t + 512] = y2;
  hb[base + t] = f2bf(y0); hb[base + t + 256] = f2bf(y1); hb[base + t + 512] = f2bf(y2);
}

__global__ void k_pool(const float* __restrict__ h, float* __restrict__ p){
  const int i = blockIdx.x * 256 + threadIdx.x;   // 12288
  const int b = i / D_, c = i % D_;
  const float* base = h + (size_t)b * NP * D_ + c;
  float s = 0.f;
  for (int n = 0; n < NP; ++n) s += base[(size_t)n * D_];
  p[i] = s * (1.f / 576.f);
}

__global__ __launch_bounds__(64) void k_fc(const float* __restrict__ p, const float* __restrict__ w,
                                           const float* __restrict__ bias, float* __restrict__ out){
  const int oi = blockIdx.x;                       // 160
  const int b = oi / 10, j = oi % 10;
  const int l = threadIdx.x;
  float s = 0.f;
  for (int c = l; c < D_; c += 64) s += p[b * D_ + c] * w[j * D_ + c];
  #pragma unroll
  for (int o = 1; o < 64; o <<= 1) s += __shfl_xor(s, o);
  if (l == 0) out[oi] = s + bias[j];
}

// ---------------- launch ------------------------------------------------------
extern "C" void kernel_launch(void* const* d_in, const int* in_sizes, int n_in,
                              void* d_out, int out_size, void* d_ws, size_t ws_size,
                              hipStream_t stream)
{
  const float* x       = (const float*)d_in[0];
  const float* patch_w = (const float*)d_in[1];
  const float* patch_b = (const float*)d_in[2];
  const float* pos_emb = (const float*)d_in[3];
  const float* ln_g    = (const float*)d_in[4];
  const float* ln_b    = (const float*)d_in[5];
  const float* Wq      = (const float*)d_in[6];
  const float* bq      = (const float*)d_in[7];
  const float* Wk      = (const float*)d_in[8];
  const float* bk      = (const float*)d_in[9];
  const float* Wv      = (const float*)d_in[10];
  const float* bv      = (const float*)d_in[11];
  const float* Wo      = (const float*)d_in[12];
  const float* bo      = (const float*)d_in[13];
  const float* W1      = (const float*)d_in[14];
  const float* b1      = (const float*)d_in[15];
  const float* W2      = (const float*)d_in[16];
  const float* b2      = (const float*)d_in[17];
  const float* fc_w    = (const float*)d_in[18];
  const float* fc_b    = (const float*)d_in[19];
  float* out = (float*)d_out;
  (void)in_sizes; (void)n_in; (void)out_size; (void)ws_size;

  char* ws = (char*)d_ws;
  size_t off = 0;
  auto alloc = [&](size_t bytes) -> char* {
    char* p = ws + off;
    off += (bytes + 255) & ~(size_t)255;
    return p;
  };
  unsigned short* wqkv    = (unsigned short*)alloc((size_t)12*2304*768*2);
  unsigned short* wo      = (unsigned short*)alloc((size_t)12*768*768*2);
  unsigned short* w1      = (unsigned short*)alloc((size_t)12*3072*768*2);
  unsigned short* w2      = (unsigned short*)alloc((size_t)12*768*3072*2);
  unsigned short* wp      = (unsigned short*)alloc((size_t)768*KPAT*2);
  float*          bqkv    = (float*)alloc((size_t)12*2304*4);
  unsigned short* patches = (unsigned short*)alloc((size_t)MROWS*KPAT*2);
  float*          hf      = (float*)alloc((size_t)MROWS*D_*4);
  unsigned short* hb      = (unsigned short*)alloc((size_t)MROWS*D_*2);
  unsigned short* qkvb    = (unsigned short*)alloc((size_t)MROWS*2304*2);
  unsigned short* ob      = (unsigned short*)alloc((size_t)MROWS*D_*2);
  unsigned short* ffb     = (unsigned short*)alloc((size_t)MROWS*3072*2);
  float*          pooled  = (float*)alloc((size_t)16*D_*4);

  // weight conversion / packing (bf16)
  k_pack_qkvw<<<2048, 256, 0, stream>>>(Wq, Wk, Wv, wqkv);
  k_pack_qkvb<<<(12*2304 + 255)/256, 256, 0, stream>>>(bq, bk, bv, bqkv);
  k_f2b<<<2048, 256, 0, stream>>>(Wo, wo, (long)12*768*768);
  k_f2b<<<2048, 256, 0, stream>>>(W1, w1, (long)12*3072*768);
  k_f2b<<<2048, 256, 0, stream>>>(W2, w2, (long)12*768*3072);
  k_patchw<<<2048, 256, 0, stream>>>(patch_w, wp);
  k_patches<<<2048, 256, 0, stream>>>(x, patches);

  // patch embed (+bias +pos) -> hf ; LN -> hf (in-place) + hb
  gemm_bt<<<72*6, 256, 0, stream>>>(patches, wp, patch_b, pos_emb,
                                    nullptr, hf, nullptr, MROWS, 768, KPAT, 0);
  k_ln<<<MROWS, 256, 0, stream>>>(hf, hb, ln_g, ln_b);

  for (int l = 0; l < 12; ++l){
    gemm_bt<<<72*18, 256, 0, stream>>>(hb, wqkv + (size_t)l*2304*768, bqkv + l*2304,
                                       nullptr, nullptr, nullptr, qkvb, MROWS, 2304, 768, 0);
    k_attn<<<576, 384, 0, stream>>>(qkvb, ob);
    gemm_bt<<<72*6, 256, 0, stream>>>(ob, wo + (size_t)l*768*768, bo + l*768,
                                      nullptr, hf, hf, hb, MROWS, 768, 768, 0);
    gemm_bt<<<72*24, 256, 0, stream>>>(hb, w1 + (size_t)l*3072*768, b1 + (size_t)l*3072,
                                       nullptr, nullptr, nullptr, ffb, MROWS, 3072, 768, 1);
    gemm_bt<<<72*6, 256, 0, stream>>>(ffb, w2 + (size_t)l*768*3072, b2 + l*768,
                                      nullptr, hf, hf, hb, MROWS, 768, 3072, 0);
  }
  k_pool<<<48, 256, 0, stream>>>(hf, pooled);
  k_fc<<<160, 64, 0, stream>>>(pooled, fc_w, fc_b, out);
}